// Round 4
// baseline (5862.324 us; speedup 1.0000x reference)
//
#include <hip/hip_runtime.h>

// ---------------- problem constants ----------------
#define VV 50000
#define EE 512
#define HH 256
#define BB 32
#define SS 1024
#define G4 1024   // 4*H

typedef __attribute__((ext_vector_type(8))) short short8;
typedef __attribute__((ext_vector_type(4))) float float4v;
typedef __attribute__((ext_vector_type(2))) float float2v;
typedef __attribute__((ext_vector_type(4))) unsigned short ushort4v;

#define MFMA(a, b, c) __builtin_amdgcn_mfma_f32_16x16x32_bf16(a, b, c, 0, 0, 0)

__device__ __forceinline__ float b2f(unsigned short u) {
  union { unsigned int i; float f; } v; v.i = ((unsigned int)u) << 16; return v.f;
}
__device__ __forceinline__ unsigned short f2b(float f) {
  union { float f; unsigned int i; } v; v.f = f;
  unsigned int u = v.i;
  return (unsigned short)((u + 0x7fffu + ((u >> 16) & 1u)) >> 16);
}
// pack 8 consecutive fp32 (16B-aligned) -> short8 of bf16
__device__ __forceinline__ short8 pack8(const float* p) {
  float4v x0 = *(const float4v*)p;
  float4v x1 = *(const float4v*)(p + 4);
  short8 r;
  r[0] = (short)f2b(x0[0]); r[1] = (short)f2b(x0[1]);
  r[2] = (short)f2b(x0[2]); r[3] = (short)f2b(x0[3]);
  r[4] = (short)f2b(x1[0]); r[5] = (short)f2b(x1[1]);
  r[6] = (short)f2b(x1[2]); r[7] = (short)f2b(x1[3]);
  return r;
}
__device__ __forceinline__ float sigm(float x) {
  return __builtin_amdgcn_rcpf(1.0f + __expf(-x));
}
__device__ __forceinline__ float tanh_f(float x) {
  return 1.0f - 2.0f * __builtin_amdgcn_rcpf(__expf(2.0f * x) + 1.0f);
}

// ---------------- kernel 1: fmask scan -> order/counts ----------------
__global__ __launch_bounds__(256) void k_scan(const int* __restrict__ fmask,
                                              int* __restrict__ order,
                                              int* __restrict__ counts) {
  __shared__ int sh[256];
  const int b = blockIdx.x;
  const int tid = threadIdx.x;
  int m0[4];
  const int base = b * SS + tid * 4;
#pragma unroll
  for (int j = 0; j < 4; ++j) m0[j] = fmask[base + j];
  const int s = m0[0] + m0[1] + m0[2] + m0[3];
  sh[tid] = s;
  __syncthreads();
  for (int off = 1; off < 256; off <<= 1) {
    int v = 0;
    if (tid >= off) v = sh[tid - off];
    __syncthreads();
    sh[tid] += v;
    __syncthreads();
  }
  const int incl = sh[tid];
  int pos = incl - s;
#pragma unroll
  for (int j = 0; j < 4; ++j) {
    if (m0[j]) order[b * SS + pos++] = tid * 4 + j;
  }
  if (tid == 255) counts[b] = incl;
}

// ---------------- kernel 2: embedding-gather + input GEMM ----------------
#define BM 128
#define BN 128
#define BK 32
#define LSTR 56

__global__ __launch_bounds__(256, 2) void k_gemm(
    const int* __restrict__ inputs, const int* __restrict__ seqlen,
    const float* __restrict__ emb,
    const float* __restrict__ Wih_f, const float* __restrict__ Wih_b,
    const float* __restrict__ bih_f, const float* __restrict__ bih_b,
    const float* __restrict__ bhh_f, const float* __restrict__ bhh_b,
    unsigned short* __restrict__ xg) {
  __shared__ short As[BM * LSTR];
  __shared__ short Bs[BN * LSTR];
  __shared__ int tokL[BM];

  const int d = blockIdx.y;
  const int mt = blockIdx.x >> 3, nt = blockIdx.x & 7;
  const int Mbase = mt * BM, Nbase = nt * BN;
  const int tid = threadIdx.x;
  const float* Wih = d ? Wih_b : Wih_f;

  if (tid < BM) {
    const int m = Mbase + tid;
    const int t = m >> 5, b = m & 31;
    int tok;
    if (d == 0) {
      tok = inputs[b * SS + t];
    } else {
      const int L = seqlen[b];
      tok = (t < L) ? inputs[b * SS + (L - 1 - t)] : 0;
    }
    tokL[tid] = tok;
  }
  __syncthreads();

  const int wave = tid >> 6, lane = tid & 63, ln = lane & 15, q = lane >> 4;
  const int wm = wave & 1, wn = wave >> 1;

  float4v acc[4][4];
#pragma unroll
  for (int mi = 0; mi < 4; ++mi)
#pragma unroll
    for (int ni = 0; ni < 4; ++ni) acc[mi][ni] = (float4v){0.f, 0.f, 0.f, 0.f};

  for (int kb = 0; kb < (EE / BK); ++kb) {
    const int k0 = kb * BK;
    if (kb) __syncthreads();
#pragma unroll
    for (int i = 0; i < 2; ++i) {
      const int c = tid + i * 256;
      const int row = c >> 2, sub = c & 3;
      const short8 av = pack8(emb + (size_t)tokL[row] * EE + k0 + sub * 8);
      *(short8*)(As + row * LSTR + sub * 8) = av;
      const short8 bv = pack8(Wih + (size_t)(Nbase + row) * EE + k0 + sub * 8);
      *(short8*)(Bs + row * LSTR + sub * 8) = bv;
    }
    __syncthreads();
    short8 af[4], bfr[4];
#pragma unroll
    for (int mi = 0; mi < 4; ++mi)
      af[mi] = *(const short8*)(As + (wm * 64 + mi * 16 + ln) * LSTR + q * 8);
#pragma unroll
    for (int ni = 0; ni < 4; ++ni)
      bfr[ni] = *(const short8*)(Bs + (wn * 64 + ni * 16 + ln) * LSTR + q * 8);
#pragma unroll
    for (int mi = 0; mi < 4; ++mi)
#pragma unroll
      for (int ni = 0; ni < 4; ++ni)
        acc[mi][ni] = MFMA(af[mi], bfr[ni], acc[mi][ni]);
  }

  const float* bih = d ? bih_b : bih_f;
  const float* bhh = d ? bhh_b : bhh_f;
  float biasv[4];
#pragma unroll
  for (int ni = 0; ni < 4; ++ni) {
    const int col = Nbase + wn * 64 + ni * 16 + ln;
    biasv[ni] = bih[col] + bhh[col];
  }
#pragma unroll
  for (int mi = 0; mi < 4; ++mi) {
    const int mrow = Mbase + wm * 64 + mi * 16 + q * 4;
    const int t = mrow >> 5, b0 = mrow & 31;
#pragma unroll
    for (int ni = 0; ni < 4; ++ni) {
      const int gcol = Nbase + wn * 64 + ni * 16 + ln;
      ushort4v pk;
#pragma unroll
      for (int r = 0; r < 4; ++r) pk[r] = f2b(acc[mi][ni][r] + biasv[ni]);
      *(ushort4v*)(xg + (((size_t)d * SS + t) * G4 + gcol) * BB + b0) = pk;
    }
  }
}

// ---------------- kernel 3: recurrence (fence-free, data-as-signal) ----------------
// 16 active wgs: (dir d) x (unit-slice k in [0,8)). W_hh slice in VGPRs.
// hbuf pre-filled with 0xFF sentinel (bf16 -NaN, unreachable: |h|<1).
// Each 8B chunk of h is written by exactly ONE lane's relaxed agent atomic
// store (MALL write-through); readers poll the data itself with relaxed agent
// atomic loads (L1/L2 bypass). A qword is either all-sentinel or final ->
// no fences, no flags, no barriers; any reordering = benign retry.
__device__ __forceinline__ void lstm_step(
    int t, const unsigned short* __restrict__ xgd, unsigned short* hb,
    const short8 (&w)[4][8], float (&c4)[4],
    unsigned short (&xc)[16], unsigned short (&xn)[16],
    int chain, int ubase, int q) {
  const unsigned long long* hq =
      (const unsigned long long*)(hb + ((size_t)t * BB + chain) * HH) + q * 2;
  unsigned long long qv[16];
  while (true) {
    bool bad = false;
#pragma unroll
    for (int i = 0; i < 16; ++i)
      qv[i] = __hip_atomic_load(hq + (i >> 1) * 8 + (i & 1),
                                __ATOMIC_RELAXED, __HIP_MEMORY_SCOPE_AGENT);
#pragma unroll
    for (int i = 0; i < 16; ++i) bad = bad || (qv[i] == ~0ULL);
    if (!__any(bad)) break;
  }

  // prefetch xg for t+1 (consumed next step; off the publish path)
  if (t + 1 < SS) {
#pragma unroll
    for (int G = 0; G < 4; ++G)
#pragma unroll
      for (int r = 0; r < 4; ++r)
        xn[G * 4 + r] =
            xgd[((size_t)(t + 1) * G4 + (G * 256 + ubase + r)) * BB + chain];
  }

  float4v acc[4];
#pragma unroll
  for (int G = 0; G < 4; ++G) acc[G] = (float4v){0.f, 0.f, 0.f, 0.f};
#pragma unroll
  for (int kt = 0; kt < 8; ++kt) {
    union { unsigned long long u[2]; short8 s; } hh;
    hh.u[0] = qv[kt * 2]; hh.u[1] = qv[kt * 2 + 1];
#pragma unroll
    for (int G = 0; G < 4; ++G) acc[G] = MFMA(w[G][kt], hh.s, acc[G]);
  }

  unsigned long long pv = 0ull;
#pragma unroll
  for (int r = 0; r < 4; ++r) {
    const float gi = acc[0][r] + b2f(xc[0 * 4 + r]);
    const float gf = acc[1][r] + b2f(xc[1 * 4 + r]);
    const float gg = acc[2][r] + b2f(xc[2 * 4 + r]);
    const float go = acc[3][r] + b2f(xc[3 * 4 + r]);
    const float cn = sigm(gf) * c4[r] + sigm(gi) * tanh_f(gg);
    c4[r] = cn;
    const float h = sigm(go) * tanh_f(cn);
    pv |= ((unsigned long long)f2b(h)) << (16 * r);
  }
  __hip_atomic_store(
      (unsigned long long*)(hb + ((size_t)(t + 1) * BB + chain) * HH + ubase),
      pv, __ATOMIC_RELAXED, __HIP_MEMORY_SCOPE_AGENT);
}

__global__ __launch_bounds__(256, 1) void k_recur(
    const float* __restrict__ Whh_f, const float* __restrict__ Whh_b,
    const unsigned short* __restrict__ xg, unsigned short* __restrict__ hbuf) {
  const int beta = blockIdx.x;
  const int xcd = beta & 7, slot = beta >> 3;   // blockIdx%8 ~ XCD (perf heuristic only)
  if (xcd >= 2) return;
  const int d = xcd, k = slot;
  const float* Whh = d ? Whh_b : Whh_f;
  const int tid = threadIdx.x;
  const int lane = tid & 63, ln = lane & 15, q = lane >> 4;
  const int wave = tid >> 6;
  const int g = wave & 1, nw = wave >> 1;
  const int chain = nw * 16 + ln;               // this lane's batch chain (C col)
  const int ubase = k * 32 + g * 16 + q * 4;    // first of this lane's 4 units (C rows)

  // loop-invariant weight fragments: A[m][kk], m=ln, kk=q*8+j
  short8 w[4][8];
#pragma unroll
  for (int G = 0; G < 4; ++G) {
    const int grow = G * 256 + k * 32 + g * 16 + ln;
#pragma unroll
    for (int kt = 0; kt < 8; ++kt)
      w[G][kt] = pack8(Whh + (size_t)grow * HH + kt * 32 + q * 8);
  }

  float c4[4] = {0.f, 0.f, 0.f, 0.f};
  unsigned short* hb = hbuf + (size_t)d * 1025 * BB * HH;
  const unsigned short* xgd = xg + (size_t)d * SS * G4 * BB;

  // xg for t=0
  unsigned short xA[16], xB[16];
#pragma unroll
  for (int G = 0; G < 4; ++G)
#pragma unroll
    for (int r = 0; r < 4; ++r)
      xA[G * 4 + r] = xgd[((size_t)0 * G4 + (G * 256 + ubase + r)) * BB + chain];

  for (int t = 0; t < SS; t += 2) {
    lstm_step(t,     xgd, hb, w, c4, xA, xB, chain, ubase, q);
    lstm_step(t + 1, xgd, hb, w, c4, xB, xA, chain, ubase, q);
  }
}

// ---------------- kernel 4: masked compaction gather -> out (fp32) ----------------
__global__ __launch_bounds__(256) void k_gather(
    const unsigned short* __restrict__ hbuf, const int* __restrict__ order,
    const int* __restrict__ counts, float* __restrict__ out) {
  const int bj = blockIdx.x;            // (b, j)
  const int b = bj >> 10, j = bj & 1023;
  const int tid = threadIdx.x;
  const int cnt = counts[b];
  float2v val = (float2v){0.f, 0.f};
  if (j < cnt) {
    const int half = tid >> 7;          // 0: forward, 1: backward
    const int e2 = (tid & 127) * 2;
    const int tsel = half ? order[b * SS + (cnt - 1 - j)] : order[b * SS + j];
    const unsigned short* src =
        hbuf + (((size_t)half * 1025 + (tsel + 1)) * BB + b) * HH + e2;
    const unsigned int u = *(const unsigned int*)src;
    val[0] = b2f((unsigned short)u);
    val[1] = b2f((unsigned short)(u >> 16));
  }
  *(float2v*)(out + (size_t)bj * 512 + tid * 2) = val;
}

// ---------------- host ----------------
extern "C" void kernel_launch(void* const* d_in, const int* in_sizes, int n_in,
                              void* d_out, int out_size, void* d_ws, size_t ws_size,
                              hipStream_t stream) {
  (void)in_sizes; (void)n_in; (void)out_size; (void)ws_size;
  const int* inputs = (const int*)d_in[0];
  const int* seqlen = (const int*)d_in[1];
  const int* fmask  = (const int*)d_in[2];
  const float* emb  = (const float*)d_in[5];
  const float* fWih = (const float*)d_in[6];
  const float* fWhh = (const float*)d_in[7];
  const float* fbih = (const float*)d_in[8];
  const float* fbhh = (const float*)d_in[9];
  const float* bWih = (const float*)d_in[10];
  const float* bWhh = (const float*)d_in[11];
  const float* bbih = (const float*)d_in[12];
  const float* bbhh = (const float*)d_in[13];
  float* out = (float*)d_out;

  char* ws = (char*)d_ws;
  int* counts = (int*)(ws + 1024);              // 32 ints
  int* order  = (int*)(ws + 16384);             // 32*1024 ints
  const size_t o_hbuf = (size_t)1 << 18;
  unsigned short* hbuf = (unsigned short*)(ws + o_hbuf);          // 2*1025*32*256 bf16
  const size_t hbuf_bytes = (size_t)2 * 1025 * BB * HH * 2;       // 33,587,200
  const size_t o_xg = o_hbuf + hbuf_bytes;
  unsigned short* xg = (unsigned short*)(ws + o_xg);              // 2*1024*1024*32 bf16

  // sentinel-fill hbuf (0xFFFF bf16 = -NaN, unreachable for h), then zero h_{-1}
  hipMemsetAsync(hbuf, 0xFF, hbuf_bytes, stream);
  hipMemsetAsync(hbuf, 0, (size_t)BB * HH * 2, stream);
  hipMemsetAsync(hbuf + (size_t)1025 * BB * HH, 0, (size_t)BB * HH * 2, stream);

  k_scan<<<32, 256, 0, stream>>>(fmask, order, counts);
  k_gemm<<<dim3(2048, 2), 256, 0, stream>>>(inputs, seqlen, emb, fWih, bWih,
                                            fbih, bbih, fbhh, bbhh, xg);
  k_recur<<<64, 256, 0, stream>>>(fWhh, bWhh, xg, hbuf);
  k_gather<<<BB * SS, 256, 0, stream>>>(hbuf, order, counts, out);
}

// Round 6
// 3581.374 us; speedup vs baseline: 1.6369x; 1.6369x over previous
//
#include <hip/hip_runtime.h>

// ---------------- problem constants ----------------
#define VV 50000
#define EE 512
#define HH 256
#define BB 32
#define SS 1024
#define G4 1024   // 4*H

typedef __attribute__((ext_vector_type(8))) short short8;
typedef __attribute__((ext_vector_type(4))) float float4v;
typedef __attribute__((ext_vector_type(2))) float float2v;
typedef __attribute__((ext_vector_type(4))) unsigned short ushort4v;

#define MFMA(a, b, c) __builtin_amdgcn_mfma_f32_16x16x32_bf16(a, b, c, 0, 0, 0)

__device__ __forceinline__ float b2f(unsigned short u) {
  union { unsigned int i; float f; } v; v.i = ((unsigned int)u) << 16; return v.f;
}
__device__ __forceinline__ unsigned short f2b(float f) {
  union { float f; unsigned int i; } v; v.f = f;
  unsigned int u = v.i;
  return (unsigned short)((u + 0x7fffu + ((u >> 16) & 1u)) >> 16);
}
// pack 8 consecutive fp32 (16B-aligned) -> short8 of bf16
__device__ __forceinline__ short8 pack8(const float* p) {
  float4v x0 = *(const float4v*)p;
  float4v x1 = *(const float4v*)(p + 4);
  short8 r;
  r[0] = (short)f2b(x0[0]); r[1] = (short)f2b(x0[1]);
  r[2] = (short)f2b(x0[2]); r[3] = (short)f2b(x0[3]);
  r[4] = (short)f2b(x1[0]); r[5] = (short)f2b(x1[1]);
  r[6] = (short)f2b(x1[2]); r[7] = (short)f2b(x1[3]);
  return r;
}
__device__ __forceinline__ float sigm(float x) {
  return __builtin_amdgcn_rcpf(1.0f + __expf(-x));
}
__device__ __forceinline__ float tanh_f(float x) {
  return 1.0f - 2.0f * __builtin_amdgcn_rcpf(__expf(2.0f * x) + 1.0f);
}

// ---------------- kernel 1: fmask scan -> order/counts ----------------
__global__ __launch_bounds__(256) void k_scan(const int* __restrict__ fmask,
                                              int* __restrict__ order,
                                              int* __restrict__ counts) {
  __shared__ int sh[256];
  const int b = blockIdx.x;
  const int tid = threadIdx.x;
  int m0[4];
  const int base = b * SS + tid * 4;
#pragma unroll
  for (int j = 0; j < 4; ++j) m0[j] = fmask[base + j];
  const int s = m0[0] + m0[1] + m0[2] + m0[3];
  sh[tid] = s;
  __syncthreads();
  for (int off = 1; off < 256; off <<= 1) {
    int v = 0;
    if (tid >= off) v = sh[tid - off];
    __syncthreads();
    sh[tid] += v;
    __syncthreads();
  }
  const int incl = sh[tid];
  int pos = incl - s;
#pragma unroll
  for (int j = 0; j < 4; ++j) {
    if (m0[j]) order[b * SS + pos++] = tid * 4 + j;
  }
  if (tid == 255) counts[b] = incl;
}

// ---------------- kernel 2: embedding-gather + input GEMM ----------------
// NEW layout: xg[d][t][b][gate] (bf16). Computed as C^T by swapping MFMA
// operands (A=W-tile rows -> C rows = gates in (q*4+r), B=emb rows -> C col
// = txb in ln), so the epilogue still writes packed 8B ushort4 stores.
#define BM 128
#define BN 128
#define BK 32
#define LSTR 56

__global__ __launch_bounds__(256, 2) void k_gemm(
    const int* __restrict__ inputs, const int* __restrict__ seqlen,
    const float* __restrict__ emb,
    const float* __restrict__ Wih_f, const float* __restrict__ Wih_b,
    const float* __restrict__ bih_f, const float* __restrict__ bih_b,
    const float* __restrict__ bhh_f, const float* __restrict__ bhh_b,
    unsigned short* __restrict__ xg) {
  __shared__ short As[BM * LSTR];
  __shared__ short Bs[BN * LSTR];
  __shared__ int tokL[BM];

  const int d = blockIdx.y;
  const int mt = blockIdx.x >> 3, nt = blockIdx.x & 7;
  const int Mbase = mt * BM, Nbase = nt * BN;
  const int tid = threadIdx.x;
  const float* Wih = d ? Wih_b : Wih_f;

  if (tid < BM) {
    const int m = Mbase + tid;
    const int t = m >> 5, b = m & 31;
    int tok;
    if (d == 0) {
      tok = inputs[b * SS + t];
    } else {
      const int L = seqlen[b];
      tok = (t < L) ? inputs[b * SS + (L - 1 - t)] : 0;
    }
    tokL[tid] = tok;
  }
  __syncthreads();

  const int wave = tid >> 6, lane = tid & 63, ln = lane & 15, q = lane >> 4;
  const int wm = wave & 1, wn = wave >> 1;

  float4v acc[4][4];   // [ni (gate tile)][mi (txb tile)]
#pragma unroll
  for (int ni = 0; ni < 4; ++ni)
#pragma unroll
    for (int mi = 0; mi < 4; ++mi) acc[ni][mi] = (float4v){0.f, 0.f, 0.f, 0.f};

  for (int kb = 0; kb < (EE / BK); ++kb) {
    const int k0 = kb * BK;
    if (kb) __syncthreads();
#pragma unroll
    for (int i = 0; i < 2; ++i) {
      const int c = tid + i * 256;
      const int row = c >> 2, sub = c & 3;
      const short8 av = pack8(emb + (size_t)tokL[row] * EE + k0 + sub * 8);
      *(short8*)(As + row * LSTR + sub * 8) = av;
      const short8 bv = pack8(Wih + (size_t)(Nbase + row) * EE + k0 + sub * 8);
      *(short8*)(Bs + row * LSTR + sub * 8) = bv;
    }
    __syncthreads();
    short8 af[4], bfr[4];
#pragma unroll
    for (int mi = 0; mi < 4; ++mi)
      af[mi] = *(const short8*)(As + (wm * 64 + mi * 16 + ln) * LSTR + q * 8);
#pragma unroll
    for (int ni = 0; ni < 4; ++ni)
      bfr[ni] = *(const short8*)(Bs + (wn * 64 + ni * 16 + ln) * LSTR + q * 8);
#pragma unroll
    for (int ni = 0; ni < 4; ++ni)
#pragma unroll
      for (int mi = 0; mi < 4; ++mi)
        acc[ni][mi] = MFMA(bfr[ni], af[mi], acc[ni][mi]);   // swapped operands
  }

  const float* bih = d ? bih_b : bih_f;
  const float* bhh = d ? bhh_b : bhh_f;
  float biasv[4][4];   // [ni][r] -- gate = Nbase + wn*64 + ni*16 + q*4 + r
#pragma unroll
  for (int ni = 0; ni < 4; ++ni)
#pragma unroll
    for (int r = 0; r < 4; ++r) {
      const int col = Nbase + wn * 64 + ni * 16 + q * 4 + r;
      biasv[ni][r] = bih[col] + bhh[col];
    }
#pragma unroll
  for (int ni = 0; ni < 4; ++ni) {
    const int gate0 = Nbase + wn * 64 + ni * 16 + q * 4;
#pragma unroll
    for (int mi = 0; mi < 4; ++mi) {
      const int m = Mbase + wm * 64 + mi * 16 + ln;
      const int t = m >> 5, b0 = m & 31;
      ushort4v pk;
#pragma unroll
      for (int r = 0; r < 4; ++r) pk[r] = f2b(acc[ni][mi][r] + biasv[ni][r]);
      *(ushort4v*)(xg + (((size_t)d * SS + t) * BB + b0) * G4 + gate0) = pk;
    }
  }
}

// ---------------- kernel 3: recurrence (aggregated-count sync) ----------------
// 16 active wgs: (dir d) x (unit-slice k in [0,8)). W_hh slice in VGPRs.
// Publish: per-lane 8B agent-scope h store -> __syncthreads (drains vmcnt:
// all stores ACKed at the MALL coherence point) -> tid0 atomicAdd cnt[t+1].
// Consume: ONLY wave0 polls cnt[t] (one same-line dword load per iteration,
// 8 pollers per direction total); waves 1-3 park on the barrier. h data read
// once after detect via MALL-coherent relaxed atomic loads. xg (transposed
// layout) prefetched one step ahead with 4 x 8B loads, issued before poll.
__global__ __launch_bounds__(256, 1) void k_recur(
    const float* __restrict__ Whh_f, const float* __restrict__ Whh_b,
    const unsigned short* __restrict__ xg, unsigned short* __restrict__ hbuf,
    int* __restrict__ cnt) {
  const int beta = blockIdx.x;
  const int xcd = beta & 7, slot = beta >> 3;   // blockIdx%8 ~ XCD (perf heuristic only)
  if (xcd >= 2) return;
  const int d = xcd, k = slot;
  const float* Whh = d ? Whh_b : Whh_f;
  const int tid = threadIdx.x;
  const int lane = tid & 63, ln = lane & 15, q = lane >> 4;
  const int wave = tid >> 6;
  const int g = wave & 1, nw = wave >> 1;
  const int chain = nw * 16 + ln;               // this lane's batch chain (C col)
  const int ubase = k * 32 + g * 16 + q * 4;    // first of this lane's 4 units (C rows)

  // loop-invariant weight fragments: A[m][kk], m=ln, kk=q*8+j
  short8 w[4][8];
#pragma unroll
  for (int G = 0; G < 4; ++G) {
    const int grow = G * 256 + k * 32 + g * 16 + ln;
#pragma unroll
    for (int kt = 0; kt < 8; ++kt)
      w[G][kt] = pack8(Whh + (size_t)grow * HH + kt * 32 + q * 8);
  }

  float c4[4] = {0.f, 0.f, 0.f, 0.f};
  unsigned short* hb = hbuf + (size_t)d * 1025 * BB * HH;
  const unsigned short* xgd = xg + (size_t)d * SS * BB * G4;
  int* cd = cnt + d * 1536;                     // cd[t] = #slices that published h_t

  // xg for t=0 (transposed layout: 4 gates x 4 units contiguous per lane)
  ushort4v xc4[4], xn4[4];
#pragma unroll
  for (int G = 0; G < 4; ++G)
    xc4[G] = *(const ushort4v*)(xgd + ((size_t)0 * BB + chain) * G4 + G * 256 + ubase);

  for (int t = 0; t < SS; ++t) {
    // prefetch next step's xg first -> overlaps the poll wait
    if (t + 1 < SS) {
#pragma unroll
      for (int G = 0; G < 4; ++G)
        xn4[G] = *(const ushort4v*)(xgd + ((size_t)(t + 1) * BB + chain) * G4 +
                                    G * 256 + ubase);
    }

    if (t > 0) {
      if (wave == 0) {
        while (__hip_atomic_load(cd + t, __ATOMIC_RELAXED,
                                 __HIP_MEMORY_SCOPE_AGENT) < 8) {}
      }
      __syncthreads();   // waves 1-3 park here; release => cnt[t]==8 observed
    }

    // h_{t-1} row for this chain: 16 x 8B MALL-coherent loads (issued together)
    const unsigned long long* hq =
        (const unsigned long long*)(hb + ((size_t)t * BB + chain) * HH) + q * 2;
    unsigned long long qv[16];
#pragma unroll
    for (int i = 0; i < 16; ++i)
      qv[i] = __hip_atomic_load(hq + (i >> 1) * 8 + (i & 1),
                                __ATOMIC_RELAXED, __HIP_MEMORY_SCOPE_AGENT);

    float4v acc[4];
#pragma unroll
    for (int G = 0; G < 4; ++G) acc[G] = (float4v){0.f, 0.f, 0.f, 0.f};
#pragma unroll
    for (int kt = 0; kt < 8; ++kt) {
      union { unsigned long long u[2]; short8 s; } hh;
      hh.u[0] = qv[kt * 2]; hh.u[1] = qv[kt * 2 + 1];
#pragma unroll
      for (int G = 0; G < 4; ++G) acc[G] = MFMA(w[G][kt], hh.s, acc[G]);
    }

    unsigned long long pv = 0ull;
#pragma unroll
    for (int r = 0; r < 4; ++r) {
      const float gi = acc[0][r] + b2f(xc4[0][r]);
      const float gf = acc[1][r] + b2f(xc4[1][r]);
      const float gg = acc[2][r] + b2f(xc4[2][r]);
      const float go = acc[3][r] + b2f(xc4[3][r]);
      const float cn = sigm(gf) * c4[r] + sigm(gi) * tanh_f(gg);
      c4[r] = cn;
      const float h = sigm(go) * tanh_f(cn);
      pv |= ((unsigned long long)f2b(h)) << (16 * r);
    }
    __hip_atomic_store(
        (unsigned long long*)(hb + ((size_t)(t + 1) * BB + chain) * HH + ubase),
        pv, __ATOMIC_RELAXED, __HIP_MEMORY_SCOPE_AGENT);
    __syncthreads();   // per-wave vmcnt(0) before barrier => all stores ACKed
    if (tid == 0)
      __hip_atomic_fetch_add(cd + t + 1, 1, __ATOMIC_RELAXED,
                             __HIP_MEMORY_SCOPE_AGENT);

#pragma unroll
    for (int G = 0; G < 4; ++G) xc4[G] = xn4[G];
  }
}

// ---------------- kernel 4: masked compaction gather -> out (fp32) ----------------
__global__ __launch_bounds__(256) void k_gather(
    const unsigned short* __restrict__ hbuf, const int* __restrict__ order,
    const int* __restrict__ counts, float* __restrict__ out) {
  const int bj = blockIdx.x;            // (b, j)
  const int b = bj >> 10, j = bj & 1023;
  const int tid = threadIdx.x;
  const int cnt = counts[b];
  float2v val = (float2v){0.f, 0.f};
  if (j < cnt) {
    const int half = tid >> 7;          // 0: forward, 1: backward
    const int e2 = (tid & 127) * 2;
    const int tsel = half ? order[b * SS + (cnt - 1 - j)] : order[b * SS + j];
    const unsigned short* src =
        hbuf + (((size_t)half * 1025 + (tsel + 1)) * BB + b) * HH + e2;
    const unsigned int u = *(const unsigned int*)src;
    val[0] = b2f((unsigned short)u);
    val[1] = b2f((unsigned short)(u >> 16));
  }
  *(float2v*)(out + (size_t)bj * 512 + tid * 2) = val;
}

// ---------------- host ----------------
extern "C" void kernel_launch(void* const* d_in, const int* in_sizes, int n_in,
                              void* d_out, int out_size, void* d_ws, size_t ws_size,
                              hipStream_t stream) {
  (void)in_sizes; (void)n_in; (void)out_size; (void)ws_size;
  const int* inputs = (const int*)d_in[0];
  const int* seqlen = (const int*)d_in[1];
  const int* fmask  = (const int*)d_in[2];
  const float* emb  = (const float*)d_in[5];
  const float* fWih = (const float*)d_in[6];
  const float* fWhh = (const float*)d_in[7];
  const float* fbih = (const float*)d_in[8];
  const float* fbhh = (const float*)d_in[9];
  const float* bWih = (const float*)d_in[10];
  const float* bWhh = (const float*)d_in[11];
  const float* bbih = (const float*)d_in[12];
  const float* bbhh = (const float*)d_in[13];
  float* out = (float*)d_out;

  char* ws = (char*)d_ws;
  int* cnt    = (int*)(ws + 0);                 // 2 x 1536 ints (dirs 6KB apart)
  int* counts = (int*)(ws + 12800);             // 32 ints
  int* order  = (int*)(ws + 16384);             // 32*1024 ints
  const size_t o_hbuf = (size_t)1 << 18;
  unsigned short* hbuf = (unsigned short*)(ws + o_hbuf);          // 2*1025*32*256 bf16
  const size_t hbuf_bytes = (size_t)2 * 1025 * BB * HH * 2;       // 33,587,200
  const size_t o_xg = o_hbuf + hbuf_bytes;
  unsigned short* xg = (unsigned short*)(ws + o_xg);              // 2*1024*32*1024 bf16

  hipMemsetAsync(cnt, 0, 2 * 1536 * sizeof(int), stream);
  // zero h_{-1} slots (ws is poisoned 0xAA before every launch)
  hipMemsetAsync(hbuf, 0, (size_t)BB * HH * 2, stream);
  hipMemsetAsync(hbuf + (size_t)1025 * BB * HH, 0, (size_t)BB * HH * 2, stream);

  k_scan<<<32, 256, 0, stream>>>(fmask, order, counts);
  k_gemm<<<dim3(2048, 2), 256, 0, stream>>>(inputs, seqlen, emb, fWih, bWih,
                                            fbih, bbih, fbhh, bbhh, xg);
  k_recur<<<64, 256, 0, stream>>>(fWhh, bWhh, xg, hbuf, cnt);
  k_gather<<<BB * SS, 256, 0, stream>>>(hbuf, order, counts, out);
}